// Round 14
// baseline (118.108 us; speedup 1.0000x reference)
//
#include <hip/hip_runtime.h>

#define VOCAB 10000
#define EMB   16
#define HID   32
#define BATCH 4096
#define TLEN  512

typedef _Float16 f16x2 __attribute__((ext_vector_type(2)));
typedef _Float16 f16x8 __attribute__((ext_vector_type(8)));

// ---------------------------------------------------------------------------
// Kernel 1: P[v][j] = b[j] + sum_e emb[v][e] * Wx[e][j]   (fp32 table in ws)
// ---------------------------------------------------------------------------
__global__ __launch_bounds__(256) void rnn_proj(
    const float* __restrict__ emb, const float* __restrict__ Wx,
    const float* __restrict__ bias, float* __restrict__ P)
{
    int tid = blockIdx.x * 256 + threadIdx.x;
    if (tid >= VOCAB * HID) return;
    int v = tid >> 5;
    int j = tid & 31;
    float acc = bias[j];
    const float* ev = emb + v * EMB;
#pragma unroll
    for (int e = 0; e < EMB; ++e) {
        acc = fmaf(ev[e], Wx[e * HID + j], acc);
    }
    P[tid] = acc;
}

// ---------------------------------------------------------------------------
// Kernel 2: max-TLP k-split fdot2 scan. ONE batch per wave -> 4096 waves =
// 4/SIMD (the most this problem can offer). Lane = (j = lane&31, kh =
// lane>>5). Each lane: half-dot over 16 i-values as 8 v_dot2_f32_f16
// (f32 accumulate); halves combined with one __shfl_xor(part, 32); pA
// added AFTER the combine (partner lane has the same pA — seeding would
// double it). h as f16 in a wave-private 64B LDS row: 2 ds_read_b128 per
// step. Weights asm-pinned (r7's VGPR=28 remat disease, fixed per r9).
// Quad-unrolled: int4 token loads + P prefetched one quad ahead (r10).
// Issue budget ~25-30 instr/wave-step; 4 waves x ~55cy =~ 220-240 cy/step.
// ---------------------------------------------------------------------------
__global__ __launch_bounds__(256)
__attribute__((amdgpu_waves_per_eu(4, 4)))
void rnn_scan(
    const int*   __restrict__ x,   const float* __restrict__ P,
    const float* __restrict__ Wh,  const float* __restrict__ Wd,
    const float* __restrict__ bd,  float* __restrict__ out)
{
    __shared__ _Float16 h_lds[4][HID];          // 4 waves x 64 B

    const int lane = threadIdx.x & 63;
    const int wave = threadIdx.x >> 6;
    const int j    = lane & 31;
    const int kh   = lane >> 5;                 // k-half: i in [kh*16, kh*16+16)
    const int b    = blockIdx.x * 4 + wave;

    // wh2[m] = { Wh[kh*16+2m][j], Wh[kh*16+2m+1][j] } -> 8 VGPRs, pinned
    f16x2 wh2[8];
#pragma unroll
    for (int m = 0; m < 8; ++m) {
        wh2[m] = (f16x2){ (_Float16)Wh[(kh * 16 + 2 * m + 0) * HID + j],
                          (_Float16)Wh[(kh * 16 + 2 * m + 1) * HID + j] };
    }
#pragma unroll
    for (int m = 0; m < 8; ++m) asm("" : "+v"(wh2[m]));   // remat-proof

    h_lds[wave][j] = (_Float16)0.0f;            // h0 = 0 (2 lanes same addr+val: ok)

    const int* xb = x + b * TLEN;               // wave-uniform

    // pipeline prologue: tokens for quads 0/1, P for quad 0
    int4 tq_cur = *(const int4*)(xb);
    int4 tq_nxt = *(const int4*)(xb + 4);
    float pc0 = P[tq_cur.x * HID + j];
    float pc1 = P[tq_cur.y * HID + j];
    float pc2 = P[tq_cur.z * HID + j];
    float pc3 = P[tq_cur.w * HID + j];

    float hj = 0.0f;
    const float TWO_LOG2E = 2.8853900817779268f;  // 2*log2(e)
    // lane's k-half = two f16x8 chunks of the 64B row
    const f16x8* hrow = (const f16x8*)(&h_lds[wave][0]) + kh * 2;

#define PAIR(U, A, B) __builtin_shufflevector((U), (U), (A), (B))
#define STEP(PV)                                                              \
    {                                                                         \
        f16x8 u0 = hrow[0], u1 = hrow[1];                                     \
        float a0 = 0.f, a1 = 0.f;                                             \
        a0 = __builtin_amdgcn_fdot2(PAIR(u0,0,1), wh2[0], a0, false);         \
        a1 = __builtin_amdgcn_fdot2(PAIR(u0,2,3), wh2[1], a1, false);         \
        a0 = __builtin_amdgcn_fdot2(PAIR(u0,4,5), wh2[2], a0, false);         \
        a1 = __builtin_amdgcn_fdot2(PAIR(u0,6,7), wh2[3], a1, false);         \
        a0 = __builtin_amdgcn_fdot2(PAIR(u1,0,1), wh2[4], a0, false);         \
        a1 = __builtin_amdgcn_fdot2(PAIR(u1,2,3), wh2[5], a1, false);         \
        a0 = __builtin_amdgcn_fdot2(PAIR(u1,4,5), wh2[6], a0, false);         \
        a1 = __builtin_amdgcn_fdot2(PAIR(u1,6,7), wh2[7], a1, false);         \
        float part = a0 + a1;                                                 \
        part += __shfl_xor(part, 32, 64);       /* combine k-halves */        \
        float z  = (PV) + part;                                               \
        float e2 = __builtin_amdgcn_exp2f(z * TWO_LOG2E);                     \
        float r  = __builtin_amdgcn_rcpf(e2 + 1.0f);                          \
        hj = fmaf(-2.0f, r, 1.0f);                                            \
        h_lds[wave][j] = (_Float16)hj;                                        \
    }

    const int NQ = TLEN / 4;                    // 128 quads, exact

    for (int k = 0; k < NQ; ++k) {
        // prefetch P for quad k+1 (tokens already resident in tq_nxt)
        float pn0 = P[tq_nxt.x * HID + j];
        float pn1 = P[tq_nxt.y * HID + j];
        float pn2 = P[tq_nxt.z * HID + j];
        float pn3 = P[tq_nxt.w * HID + j];
        // prefetch token quad k+2 (clamped; tail values unused)
        int  q2i = (k + 2 < NQ) ? (k + 2) : (NQ - 1);
        int4 tq2 = *(const int4*)(xb + 4 * q2i);

        STEP(pc0)
        STEP(pc1)
        STEP(pc2)
        STEP(pc3)

        pc0 = pn0; pc1 = pn1; pc2 = pn2; pc3 = pn3;
        tq_nxt = tq2;
    }
#undef STEP
#undef PAIR

    // out[b] = sigmoid(sum_j h_j * Wd[j] + bd)
    float s = hj * Wd[j];
#pragma unroll
    for (int off = 16; off > 0; off >>= 1)
        s += __shfl_xor(s, off, 32);            // reduce within 32-lane group
    if (lane == 0) {
        float logit = s + bd[0];
        out[b] = 1.0f / (1.0f + __expf(-logit)); // fp32 output
    }
}

// ---------------------------------------------------------------------------
extern "C" void kernel_launch(void* const* d_in, const int* in_sizes, int n_in,
                              void* d_out, int out_size, void* d_ws, size_t ws_size,
                              hipStream_t stream)
{
    const int*   x   = (const int*)  d_in[0];
    const float* emb = (const float*)d_in[1];
    const float* Wx  = (const float*)d_in[2];
    const float* Wh  = (const float*)d_in[3];
    const float* bia = (const float*)d_in[4];
    const float* Wd  = (const float*)d_in[5];
    const float* bd  = (const float*)d_in[6];
    float* out = (float*)d_out;

    float* P = (float*)d_ws;                    // VOCAB*HID*4 = 1.28 MB

    rnn_proj<<<(VOCAB * HID + 255) / 256, 256, 0, stream>>>(emb, Wx, bia, P);
    rnn_scan<<<BATCH / 4, 256, 0, stream>>>(x, P, Wh, Wd, bd, out);
}